// Round 2
// baseline (5200.656 us; speedup 1.0000x reference)
//
#include <hip/hip_runtime.h>
#include <math.h>

// HolyLossNetwork: fused task-repr + pairwise symmetric-KL + log_softmax.
// fp32 correctness-first implementation (round 1 resubmit — round 1 hit a
// GPU-broker acquisition timeout; no bench evidence yet). No MFMA yet.
//
// ws layout (floats):
//   wt   [512][1024]   pad-copy of W_fe (stride 1024 for aligned float4)
//   z    [4096][2048]  task repr (rows 0..2047 train, 2048..4095 test)
//   lv   [4096][2048]  clipped logvar
//   Am   [2048][8192]  train-side KL operand [P | r | q | t]
//   Bm   [2048][8192]  test-side  KL operand [r' | P' | -2t' | -2q']
//   ctr  [2048], cte [2048]  per-row scalar terms
// total ~194 MiB.

#define NEPI 2048
#define NSH  32
#define IND  512
#define NFEAT 1023
#define DREP 2048

__device__ __forceinline__ float wave_sum(float v) {
#pragma unroll
  for (int m = 1; m < 64; m <<= 1) v += __shfl_xor(v, m, 64);
  return v;
}
__device__ __forceinline__ float wave_max(float v) {
#pragma unroll
  for (int m = 1; m < 64; m <<= 1) v = fmaxf(v, __shfl_xor(v, m, 64));
  return v;
}

// ---------------- pad-copy W_fe [512][1023] -> wt [512][1024] ----------------
__global__ __launch_bounds__(256) void k_padw(const float* __restrict__ w,
                                              float* __restrict__ wt) {
  int idx = blockIdx.x * 256 + threadIdx.x;  // 512*1024 total
  if (idx >= 512 * 1024) return;
  int k = idx >> 10, f = idx & 1023;
  wt[idx] = (f < NFEAT) ? w[k * NFEAT + f] : 0.f;
}

// ---------------- fused FE GEMM + mean/std over shots ----------------
// grid (4096 episodes, 8 f-chunks), block 256.
// LDS: inputs[e] stored k-major [512][32] -> conflict-free ds_read_b128.
__global__ __launch_bounds__(256) void k_fe(const float* __restrict__ in_tr,
                                            const float* __restrict__ in_te,
                                            const float* __restrict__ b_fe,
                                            const float* __restrict__ wt,
                                            float* __restrict__ z) {
  __shared__ float a_lds[IND][NSH];  // 64 KiB
  const int e = blockIdx.x;
  const float* src = (e < NEPI) ? in_tr + (size_t)e * NSH * IND
                                : in_te + (size_t)(e - NEPI) * NSH * IND;
#pragma unroll
  for (int i = 0; i < 16; i++) {
    int linear = i * 1024 + threadIdx.x * 4;
    float4 v = *(const float4*)&src[linear];
    int s = linear >> 9;
    int k = linear & 511;
    a_lds[k + 0][s] = v.x;
    a_lds[k + 1][s] = v.y;
    a_lds[k + 2][s] = v.z;
    a_lds[k + 3][s] = v.w;
  }
  __syncthreads();

  const int fq = threadIdx.x >> 3;       // 0..31
  const int sq = threadIdx.x & 7;        // 0..7
  const int f0 = blockIdx.y * 128 + fq * 4;
  const int s0 = sq * 4;

  float acc[4][4] = {{0.f}};
#pragma unroll 4
  for (int k = 0; k < IND; k++) {
    const float4 av = *(const float4*)&a_lds[k][s0];
    const float4 wv = *(const float4*)&wt[(size_t)k * 1024 + f0];  // f0<=1020, +3 in pad
    float a4[4] = {av.x, av.y, av.z, av.w};
    float w4[4] = {wv.x, wv.y, wv.z, wv.w};
#pragma unroll
    for (int si = 0; si < 4; si++)
#pragma unroll
      for (int fi = 0; fi < 4; fi++)
        acc[si][fi] = fmaf(a4[si], w4[fi], acc[si][fi]);
  }

#pragma unroll
  for (int fi = 0; fi < 4; fi++) {
    int f = f0 + fi;
    bool valid = f < NFEAT;
    float bf = valid ? b_fe[f] : 0.f;
    float sum = 0.f, sqs = 0.f;
#pragma unroll
    for (int si = 0; si < 4; si++) {
      float phi = acc[si][fi] + bf;
      sum += phi;
      sqs += phi * phi;
    }
#pragma unroll
    for (int m = 1; m < 8; m <<= 1) {
      sum += __shfl_xor(sum, m, 64);
      sqs += __shfl_xor(sqs, m, 64);
    }
    if (sq == 0 && valid) {
      float mean = sum * (1.f / 32.f);
      float var = (sqs - 32.f * mean * mean) * (1.f / 31.f);
      var = fmaxf(var, 0.f);
      // x = [target, phis] -> feature f lands at column 1+f; std at 1024+1+f
      z[(size_t)e * DREP + 1 + f] = mean;
      z[(size_t)e * DREP + 1024 + 1 + f] = sqrtf(var);
    }
  }
}

// ---------------- targets column mean/std -> z[:,0], z[:,1024] ----------------
__global__ __launch_bounds__(64) void k_tgt(const float* __restrict__ ttr,
                                            const float* __restrict__ tte,
                                            float* __restrict__ z) {
  const int e = blockIdx.x;
  const int lane = threadIdx.x;
  const float* src = (e < NEPI) ? ttr + (size_t)e * NSH : tte + (size_t)(e - NEPI) * NSH;
  float v = (lane < NSH) ? src[lane] : 0.f;
  float s = v, q = v * v;
#pragma unroll
  for (int m = 1; m < 32; m <<= 1) {
    s += __shfl_xor(s, m, 64);
    q += __shfl_xor(q, m, 64);
  }
  if (lane == 0) {
    float mean = s * (1.f / 32.f);
    float var = (q - 32.f * mean * mean) * (1.f / 31.f);
    var = fmaxf(var, 0.f);
    z[(size_t)e * DREP + 0] = mean;
    z[(size_t)e * DREP + 1024] = sqrtf(var);
  }
}

// ---------------- lv = clip(z @ W_lv + b_lv, -9, 1) ----------------
// M=4096, N=2048, K=2048. 64x64 tile, BK=16, 256 threads, 4x4 micro.
__global__ __launch_bounds__(256) void k_lv(const float* __restrict__ z,
                                            const float* __restrict__ wlv,
                                            const float* __restrict__ blv,
                                            float* __restrict__ lv) {
  __shared__ float As[16][64];
  __shared__ float Bs[16][64];
  const int i0 = blockIdx.y * 64, j0 = blockIdx.x * 64;
  const int tid = threadIdx.x;
  const int ty = tid >> 4, tx = tid & 15;
  float acc[4][4] = {{0.f}};

  const int ra = tid >> 2, ca = (tid & 3) * 4;        // A stage: 64 rows x 4 k-quads
  const int rb = tid >> 4, cb = (tid & 15) * 4;       // B stage: 16 rows x 16 col-quads

  for (int k0 = 0; k0 < DREP; k0 += 16) {
    float4 av = *(const float4*)&z[(size_t)(i0 + ra) * DREP + k0 + ca];
    As[ca + 0][ra] = av.x;
    As[ca + 1][ra] = av.y;
    As[ca + 2][ra] = av.z;
    As[ca + 3][ra] = av.w;
    float4 bv = *(const float4*)&wlv[(size_t)(k0 + rb) * DREP + j0 + cb];
    *(float4*)&Bs[rb][cb] = bv;
    __syncthreads();
#pragma unroll
    for (int k = 0; k < 16; k++) {
      const float4 a4 = *(const float4*)&As[k][ty * 4];
      const float4 b4 = *(const float4*)&Bs[k][tx * 4];
      float aa[4] = {a4.x, a4.y, a4.z, a4.w};
      float bb[4] = {b4.x, b4.y, b4.z, b4.w};
#pragma unroll
      for (int ii = 0; ii < 4; ii++)
#pragma unroll
        for (int jj = 0; jj < 4; jj++)
          acc[ii][jj] = fmaf(aa[ii], bb[jj], acc[ii][jj]);
    }
    __syncthreads();
  }
#pragma unroll
  for (int ii = 0; ii < 4; ii++) {
    int i = i0 + ty * 4 + ii;
    int j = j0 + tx * 4;
    float4 o;
    float* po = (float*)&o;
#pragma unroll
    for (int jj = 0; jj < 4; jj++) {
      float v = acc[ii][jj] + blv[j + jj];
      po[jj] = fminf(fmaxf(v, -9.f), 1.f);
    }
    *(float4*)&lv[(size_t)i * DREP + j] = o;
  }
}

// ---------------- build KL operand matrices + row scalars ----------------
__global__ __launch_bounds__(256) void k_tf(const float* __restrict__ z,
                                            const float* __restrict__ lv,
                                            float* __restrict__ Am,
                                            float* __restrict__ Bm,
                                            float* __restrict__ ctr,
                                            float* __restrict__ cte) {
  const int e = blockIdx.x;
  const bool train = e < NEPI;
  const int row = train ? e : e - NEPI;
  const float* zr = z + (size_t)e * DREP;
  const float* lr = lv + (size_t)e * DREP;
  float* o = (train ? Am : Bm) + (size_t)row * 4 * DREP;
  float ssum = 0.f, lsum = 0.f;
  for (int d = threadIdx.x; d < DREP; d += 256) {
    float mu = zr[d], l = lr[d];
    float ex = expf(l);
    float rx = expf(-l);
    float P = fmaf(mu, mu, ex);
    float t = mu * rx;
    if (train) {
      o[d] = P;
      o[DREP + d] = rx;
      o[2 * DREP + d] = mu;
      o[3 * DREP + d] = t;
    } else {
      o[d] = rx;
      o[DREP + d] = P;
      o[2 * DREP + d] = -2.f * t;
      o[3 * DREP + d] = -2.f * mu;
    }
    ssum += mu * mu * rx;
    lsum += l;
  }
  float s1 = wave_sum(ssum), s2 = wave_sum(lsum);
  __shared__ float rsa[4], rsb[4];
  int wid = threadIdx.x >> 6;
  if ((threadIdx.x & 63) == 0) { rsa[wid] = s1; rsb[wid] = s2; }
  __syncthreads();
  if (threadIdx.x == 0) {
    float S = rsa[0] + rsa[1] + rsa[2] + rsa[3];
    float L = rsb[0] + rsb[1] + rsb[2] + rsb[3];
    // c = 0.5*sum(mu^2 e^-lv) + sum(lv) + 0.5*D*ln(2*pi*e) [per side: 1024*ln(2pi e)] - D/2
    float c = 0.5f * S + L + 2905.98611600317f - 1024.0f;
    (train ? ctr : cte)[row] = c;
  }
}

// ---------------- score GEMM (NT, K=8192) + scalars -> d_out ----------------
__global__ __launch_bounds__(256) void k_score(const float* __restrict__ Am,
                                               const float* __restrict__ Bm,
                                               const float* __restrict__ ctr,
                                               const float* __restrict__ cte,
                                               float* __restrict__ out) {
  __shared__ float As[16][64];
  __shared__ float Bs[16][64];
  const int i0 = blockIdx.y * 64, j0 = blockIdx.x * 64;
  const int tid = threadIdx.x;
  const int ty = tid >> 4, tx = tid & 15;
  float acc[4][4] = {{0.f}};

  const int r = tid >> 2, c4 = (tid & 3) * 4;

  for (int k0 = 0; k0 < 4 * DREP; k0 += 16) {
    float4 av = *(const float4*)&Am[(size_t)(i0 + r) * (4 * DREP) + k0 + c4];
    As[c4 + 0][r] = av.x;
    As[c4 + 1][r] = av.y;
    As[c4 + 2][r] = av.z;
    As[c4 + 3][r] = av.w;
    float4 bv = *(const float4*)&Bm[(size_t)(j0 + r) * (4 * DREP) + k0 + c4];
    Bs[c4 + 0][r] = bv.x;
    Bs[c4 + 1][r] = bv.y;
    Bs[c4 + 2][r] = bv.z;
    Bs[c4 + 3][r] = bv.w;
    __syncthreads();
#pragma unroll
    for (int k = 0; k < 16; k++) {
      const float4 a4 = *(const float4*)&As[k][ty * 4];
      const float4 b4 = *(const float4*)&Bs[k][tx * 4];
      float aa[4] = {a4.x, a4.y, a4.z, a4.w};
      float bb[4] = {b4.x, b4.y, b4.z, b4.w};
#pragma unroll
      for (int ii = 0; ii < 4; ii++)
#pragma unroll
        for (int jj = 0; jj < 4; jj++)
          acc[ii][jj] = fmaf(aa[ii], bb[jj], acc[ii][jj]);
    }
    __syncthreads();
  }
#pragma unroll
  for (int ii = 0; ii < 4; ii++) {
    int i = i0 + ty * 4 + ii;
    int j = j0 + tx * 4;
    float ci = ctr[i];
    float4 o;
    float* po = (float*)&o;
#pragma unroll
    for (int jj = 0; jj < 4; jj++)
      po[jj] = 0.5f * acc[ii][jj] + ci + cte[j + jj];
    *(float4*)&out[(size_t)i * DREP + j] = o;
  }
}

// ---------------- in-place log_softmax(-score) + classes ----------------
__global__ __launch_bounds__(256) void k_sm(float* __restrict__ out) {
  const int row = blockIdx.x;
  float* p = out + (size_t)row * DREP;
  float v[8];
  float mx = -1e30f;
#pragma unroll
  for (int q = 0; q < 8; q++) {
    v[q] = -p[threadIdx.x + 256 * q];
    mx = fmaxf(mx, v[q]);
  }
  __shared__ float red1[4], red2[4];
  float wm = wave_max(mx);
  int wid = threadIdx.x >> 6;
  if ((threadIdx.x & 63) == 0) red1[wid] = wm;
  __syncthreads();
  mx = fmaxf(fmaxf(red1[0], red1[1]), fmaxf(red1[2], red1[3]));
  float s = 0.f;
#pragma unroll
  for (int q = 0; q < 8; q++) s += expf(v[q] - mx);
  float ws = wave_sum(s);
  if ((threadIdx.x & 63) == 0) red2[wid] = ws;
  __syncthreads();
  float S = red2[0] + red2[1] + red2[2] + red2[3];
  float L = logf(S);
#pragma unroll
  for (int q = 0; q < 8; q++) p[threadIdx.x + 256 * q] = v[q] - mx - L;
  if (threadIdx.x == 0) out[(size_t)DREP * DREP + row] = (float)row;
}

extern "C" void kernel_launch(void* const* d_in, const int* in_sizes, int n_in,
                              void* d_out, int out_size, void* d_ws, size_t ws_size,
                              hipStream_t stream) {
  const float* in_tr = (const float*)d_in[0];
  const float* tg_tr = (const float*)d_in[1];
  const float* in_te = (const float*)d_in[2];
  const float* tg_te = (const float*)d_in[3];
  const float* W_fe  = (const float*)d_in[4];
  const float* b_fe  = (const float*)d_in[5];
  const float* W_lv  = (const float*)d_in[6];
  const float* b_lv  = (const float*)d_in[7];
  float* out = (float*)d_out;
  float* ws = (float*)d_ws;

  float* wt  = ws;                                   // 512*1024
  float* z   = wt + (size_t)512 * 1024;              // 4096*2048
  float* lv  = z + (size_t)4096 * 2048;              // 4096*2048
  float* Am  = lv + (size_t)4096 * 2048;             // 2048*8192
  float* Bm  = Am + (size_t)2048 * 8192;             // 2048*8192
  float* ctr = Bm + (size_t)2048 * 8192;             // 2048
  float* cte = ctr + 2048;                           // 2048

  k_padw<<<2048, 256, 0, stream>>>(W_fe, wt);
  k_fe<<<dim3(4096, 8), 256, 0, stream>>>(in_tr, in_te, b_fe, wt, z);
  k_tgt<<<4096, 64, 0, stream>>>(tg_tr, tg_te, z);
  k_lv<<<dim3(32, 64), 256, 0, stream>>>(z, W_lv, b_lv, lv);
  k_tf<<<4096, 256, 0, stream>>>(z, lv, Am, Bm, ctr, cte);
  k_score<<<dim3(32, 32), 256, 0, stream>>>(Am, Bm, ctr, cte, out);
  k_sm<<<2048, 256, 0, stream>>>(out);
}

// Round 3
// 1638.185 us; speedup vs baseline: 3.1746x; 3.1746x over previous
//
#include <hip/hip_runtime.h>
#include <math.h>

// HolyLossNetwork round 3: all three GEMMs -> bf16 MFMA (16x16x32), one
// shared NT core, FE stats fused in-epilogue. fp32 elsewhere.
//
// ws layout (bytes):
//   wtT   [1024][512]  bf16   1 MiB   (W_fe^T, row 1023 = 0 pad)
//   wlvT  [2048][2048] bf16   8 MiB   (W_lv^T)
//   z     [4096][2048] f32   32 MiB
//   zb    [4096][2048] bf16  16 MiB
//   ctr, cte [2048] f32
//   zone2 (aliased):
//     xb  [131072][512] bf16 128 MiB  (dead after FE GEMM)
//     lv  [4096][2048] f32 | Am [2048][8192] bf16 | Bm [2048][8192] bf16
// peak 185 MiB (< proven 194 MiB).

#define NEPI 2048
#define NSH  32
#define IND  512
#define NFEAT 1023
#define DREP 2048

typedef short s16x8 __attribute__((ext_vector_type(8)));
typedef float f32x4 __attribute__((ext_vector_type(4)));

__device__ __forceinline__ ushort f2bf(float f) {
  union { float f; unsigned u; } x; x.f = f;
  unsigned r = x.u + 0x7fffu + ((x.u >> 16) & 1u);
  return (ushort)(r >> 16);
}
__device__ __forceinline__ unsigned pack2(ushort a, ushort b) {
  return (unsigned)a | ((unsigned)b << 16);
}
__device__ __forceinline__ float wave_sum(float v) {
#pragma unroll
  for (int m = 1; m < 64; m <<= 1) v += __shfl_xor(v, m, 64);
  return v;
}
__device__ __forceinline__ float wave_max(float v) {
#pragma unroll
  for (int m = 1; m < 64; m <<= 1) v = fmaxf(v, __shfl_xor(v, m, 64));
  return v;
}

// ---------------- fp32 -> bf16 bulk convert (8 elems/thread/iter) ------------
__global__ __launch_bounds__(256) void k_conv(const float* __restrict__ src,
                                              ushort* __restrict__ dst, int n8) {
  int stride = gridDim.x * 256;
  for (int g = blockIdx.x * 256 + threadIdx.x; g < n8; g += stride) {
    const float4* s = (const float4*)src + 2 * (size_t)g;
    float4 a = s[0], b = s[1];
    uint4 o;
    o.x = pack2(f2bf(a.x), f2bf(a.y));
    o.y = pack2(f2bf(a.z), f2bf(a.w));
    o.z = pack2(f2bf(b.x), f2bf(b.y));
    o.w = pack2(f2bf(b.z), f2bf(b.w));
    *(uint4*)(dst + 8 * (size_t)g) = o;
  }
}

// ---------------- W_fe [512][1023] f32 -> wtT [1024][512] bf16 ----------------
__global__ __launch_bounds__(256) void k_wt(const float* __restrict__ w,
                                            ushort* __restrict__ wtT) {
  int f = blockIdx.x;          // 0..1023
  int k0 = threadIdx.x * 2;    // 0..510
  ushort2 o;
  if (f < NFEAT) {
    o.x = f2bf(w[(size_t)k0 * NFEAT + f]);
    o.y = f2bf(w[(size_t)(k0 + 1) * NFEAT + f]);
  } else {
    o.x = 0; o.y = 0;
  }
  *(ushort2*)&wtT[(size_t)f * IND + k0] = o;
}

// ---------------- W_lv [2048][2048] f32 -> wlvT [2048][2048] bf16 -------------
__global__ __launch_bounds__(256) void k_wlvT(const float* __restrict__ w,
                                              ushort* __restrict__ wT) {
  __shared__ float t[64][65];
  const int kb = blockIdx.x * 64, jb = blockIdx.y * 64;
  const int tid = threadIdx.x;
  {
    int c4 = (tid & 15) * 4;
#pragma unroll
    for (int i = 0; i < 4; i++) {
      int r = (tid >> 4) + i * 16;
      float4 v = *(const float4*)&w[(size_t)(kb + r) * DREP + jb + c4];
      t[r][c4 + 0] = v.x; t[r][c4 + 1] = v.y; t[r][c4 + 2] = v.z; t[r][c4 + 3] = v.w;
    }
  }
  __syncthreads();
  {
    int jr = tid >> 2;         // 0..63 output row (j)
    int kq = (tid & 3) * 16;   // k chunk
    ushort tmp[16];
#pragma unroll
    for (int q = 0; q < 16; q++) tmp[q] = f2bf(t[kq + q][jr]);
    uint4 o0, o1;
    o0.x = pack2(tmp[0], tmp[1]);   o0.y = pack2(tmp[2], tmp[3]);
    o0.z = pack2(tmp[4], tmp[5]);   o0.w = pack2(tmp[6], tmp[7]);
    o1.x = pack2(tmp[8], tmp[9]);   o1.y = pack2(tmp[10], tmp[11]);
    o1.z = pack2(tmp[12], tmp[13]); o1.w = pack2(tmp[14], tmp[15]);
    ushort* d = &wT[(size_t)(jb + jr) * DREP + kb + kq];
    *(uint4*)d = o0;
    *(uint4*)(d + 8) = o1;
  }
}

// ---------------- unified bf16 NT MFMA GEMM, 128x128 tile, BK=64 --------------
// MODE 0 = FE (fused mean/std epilogue -> z,zb), 1 = LV (bias+clip -> lv),
// MODE 2 = SC (0.5*acc + ctr + cte -> out).
template <int MODE>
__global__ __launch_bounds__(256) void gemm_nt(
    const ushort* __restrict__ A, const ushort* __restrict__ B,
    int lda, int ldb, int K,
    const float* __restrict__ bias,
    float* __restrict__ outf, ushort* __restrict__ outb,
    const float* __restrict__ ctr, const float* __restrict__ cte) {
  __shared__ uint4 lsa4[1024];  // A tile [128 rows][64 k] bf16, XOR-swizzled
  __shared__ uint4 lsb4[1024];  // B tile [128 rows][64 k]
  char* const lsa = (char*)lsa4;
  char* const lsb = (char*)lsb4;
  const int tid = threadIdx.x;
  const int lane = tid & 63;
  const int wid = tid >> 6;
  const int wr = wid >> 1, wc = wid & 1;          // 2x2 waves of 64x64
  const int i0 = blockIdx.y * 128, j0 = blockIdx.x * 128;

  // staging: thread -> (row = tid>>1, half = tid&1) covering 32 k-elems (64B)
  const int srow = tid >> 1;
  const int cb = (tid & 1) * 64;                  // byte col base
  const int ssw = (srow & 7) << 4;
  const ushort* pa = A + (size_t)(i0 + srow) * lda + (tid & 1) * 32;
  const ushort* pb = B + (size_t)(j0 + srow) * ldb + (tid & 1) * 32;
  char* const wa = lsa + srow * 128;
  char* const wb = lsb + srow * 128;

  f32x4 acc[4][4];
  const f32x4 zero = {0.f, 0.f, 0.f, 0.f};
#pragma unroll
  for (int m = 0; m < 4; m++)
#pragma unroll
    for (int n = 0; n < 4; n++) acc[m][n] = zero;

  uint4 av[4], bv[4];
#pragma unroll
  for (int q = 0; q < 4; q++) {
    av[q] = *(const uint4*)(pa + q * 8);
    bv[q] = *(const uint4*)(pb + q * 8);
  }

  const int rswz = (lane & 7) << 4;               // row&7 == lane&7 for frag rows
  const int ra_row = wr * 64 + (lane & 15);
  const int rb_row = wc * 64 + (lane & 15);
  const int kgrp = (lane >> 4) * 16;              // byte offset of 8-elem k group

  for (int kt = 0; kt < K; kt += 64) {
    __syncthreads();                              // prev compute done
#pragma unroll
    for (int q = 0; q < 4; q++) {
      *(uint4*)(wa + ((cb + q * 16) ^ ssw)) = av[q];
      *(uint4*)(wb + ((cb + q * 16) ^ ssw)) = bv[q];
    }
    __syncthreads();
    if (kt + 64 < K) {                            // prefetch next tile into regs
#pragma unroll
      for (int q = 0; q < 4; q++) {
        av[q] = *(const uint4*)(pa + kt + 64 + q * 8);
        bv[q] = *(const uint4*)(pb + kt + 64 + q * 8);
      }
    }
#pragma unroll
    for (int ks = 0; ks < 2; ks++) {
      s16x8 af[4], bf[4];
#pragma unroll
      for (int m = 0; m < 4; m++) {
        int row = ra_row + m * 16;
        af[m] = *(const s16x8*)(lsa + row * 128 + ((ks * 64 + kgrp) ^ rswz));
      }
#pragma unroll
      for (int n = 0; n < 4; n++) {
        int row = rb_row + n * 16;
        bf[n] = *(const s16x8*)(lsb + row * 128 + ((ks * 64 + kgrp) ^ rswz));
      }
#pragma unroll
      for (int m = 0; m < 4; m++)
#pragma unroll
        for (int n = 0; n < 4; n++)
          acc[m][n] = __builtin_amdgcn_mfma_f32_16x16x32_bf16(af[m], bf[n], acc[m][n], 0, 0, 0);
    }
  }

  if constexpr (MODE == 0) {
    // fused mean/std over 32 shots: wave rows = 2 episodes (frag pairs).
    const int e_base = (i0 + wr * 64) >> 5;       // absolute episode row (0..4094)
    const int colbase = j0 + wc * 64;
#pragma unroll
    for (int n = 0; n < 4; n++) {
      int f = colbase + n * 16 + (lane & 15);     // feature index (0..1023)
      float b = (f < NFEAT) ? bias[f] : 0.f;
#pragma unroll
      for (int el = 0; el < 2; el++) {
        float Sa = 0.f, Sq = 0.f;
#pragma unroll
        for (int mm = 0; mm < 2; mm++) {
          f32x4 v4 = acc[el * 2 + mm][n];
#pragma unroll
          for (int j = 0; j < 4; j++) { float v = v4[j]; Sa += v; Sq += v * v; }
        }
        Sa += __shfl_xor(Sa, 16, 64); Sq += __shfl_xor(Sq, 16, 64);
        Sa += __shfl_xor(Sa, 32, 64); Sq += __shfl_xor(Sq, 32, 64);
        if ((lane >> 4) == 0 && f < NFEAT) {
          float sphi = Sa + 32.f * b;
          float sphi2 = Sq + 2.f * b * Sa + 32.f * b * b;
          float mean = sphi * (1.f / 32.f);
          float var = (sphi2 - 32.f * mean * mean) * (1.f / 31.f);
          var = fmaxf(var, 0.f);
          float sd = sqrtf(var);
          int e = e_base + el;
          outf[(size_t)e * DREP + 1 + f] = mean;
          outf[(size_t)e * DREP + 1025 + f] = sd;
          outb[(size_t)e * DREP + 1 + f] = f2bf(mean);
          outb[(size_t)e * DREP + 1025 + f] = f2bf(sd);
        }
      }
    }
  } else {
#pragma unroll
    for (int m = 0; m < 4; m++) {
#pragma unroll
      for (int j = 0; j < 4; j++) {
        int i = i0 + wr * 64 + m * 16 + (lane >> 4) * 4 + j;
        float rowc = (MODE == 2) ? ctr[i] : 0.f;
#pragma unroll
        for (int n = 0; n < 4; n++) {
          int c = j0 + wc * 64 + n * 16 + (lane & 15);
          float v = acc[m][n][j];
          if constexpr (MODE == 1) {
            v += bias[c];
            v = fminf(fmaxf(v, -9.f), 1.f);
          } else {
            v = 0.5f * v + rowc + cte[c];
          }
          outf[(size_t)i * DREP + c] = v;
        }
      }
    }
  }
}

// ---------------- targets column mean/std -> z/zb cols 0,1024 ----------------
__global__ __launch_bounds__(64) void k_tgt(const float* __restrict__ ttr,
                                            const float* __restrict__ tte,
                                            float* __restrict__ z,
                                            ushort* __restrict__ zb) {
  const int e = blockIdx.x;
  const int lane = threadIdx.x;
  const float* src = (e < NEPI) ? ttr + (size_t)e * NSH : tte + (size_t)(e - NEPI) * NSH;
  float v = (lane < NSH) ? src[lane] : 0.f;
  float s = v, q = v * v;
#pragma unroll
  for (int m = 1; m < 32; m <<= 1) {
    s += __shfl_xor(s, m, 64);
    q += __shfl_xor(q, m, 64);
  }
  if (lane == 0) {
    float mean = s * (1.f / 32.f);
    float var = (q - 32.f * mean * mean) * (1.f / 31.f);
    var = fmaxf(var, 0.f);
    float sd = sqrtf(var);
    z[(size_t)e * DREP + 0] = mean;
    z[(size_t)e * DREP + 1024] = sd;
    zb[(size_t)e * DREP + 0] = f2bf(mean);
    zb[(size_t)e * DREP + 1024] = f2bf(sd);
  }
}

// ---------------- KL operand matrices (bf16) + row scalars -------------------
__global__ __launch_bounds__(256) void k_tf(const float* __restrict__ z,
                                            const float* __restrict__ lv,
                                            ushort* __restrict__ Am,
                                            ushort* __restrict__ Bm,
                                            float* __restrict__ ctr,
                                            float* __restrict__ cte) {
  const int e = blockIdx.x;
  const bool train = e < NEPI;
  const int row = train ? e : e - NEPI;
  const float* zr = z + (size_t)e * DREP;
  const float* lr = lv + (size_t)e * DREP;
  ushort* o = (train ? Am : Bm) + (size_t)row * 4 * DREP;
  float ssum = 0.f, lsum = 0.f;
  for (int d = threadIdx.x; d < DREP; d += 256) {
    float mu = zr[d], l = lr[d];
    float ex = expf(l);
    float rx = expf(-l);
    float P = fmaf(mu, mu, ex);
    float t = mu * rx;
    if (train) {
      o[d] = f2bf(P);
      o[DREP + d] = f2bf(rx);
      o[2 * DREP + d] = f2bf(mu);
      o[3 * DREP + d] = f2bf(t);
    } else {
      o[d] = f2bf(rx);
      o[DREP + d] = f2bf(P);
      o[2 * DREP + d] = f2bf(-2.f * t);
      o[3 * DREP + d] = f2bf(-2.f * mu);
    }
    ssum += mu * mu * rx;
    lsum += l;
  }
  float s1 = wave_sum(ssum), s2 = wave_sum(lsum);
  __shared__ float rsa[4], rsb[4];
  int wid = threadIdx.x >> 6;
  if ((threadIdx.x & 63) == 0) { rsa[wid] = s1; rsb[wid] = s2; }
  __syncthreads();
  if (threadIdx.x == 0) {
    float S = rsa[0] + rsa[1] + rsa[2] + rsa[3];
    float L = rsb[0] + rsb[1] + rsb[2] + rsb[3];
    float c = 0.5f * S + L + 2905.98611600317f - 1024.0f;
    (train ? ctr : cte)[row] = c;
  }
}

// ---------------- in-place log_softmax(-score) + classes ---------------------
__global__ __launch_bounds__(256) void k_sm(float* __restrict__ out) {
  const int row = blockIdx.x;
  float* p = out + (size_t)row * DREP;
  float v[8];
  float mx = -1e30f;
#pragma unroll
  for (int q = 0; q < 8; q++) {
    v[q] = -p[threadIdx.x + 256 * q];
    mx = fmaxf(mx, v[q]);
  }
  __shared__ float red1[4], red2[4];
  float wm = wave_max(mx);
  int wid = threadIdx.x >> 6;
  if ((threadIdx.x & 63) == 0) red1[wid] = wm;
  __syncthreads();
  mx = fmaxf(fmaxf(red1[0], red1[1]), fmaxf(red1[2], red1[3]));
  float s = 0.f;
#pragma unroll
  for (int q = 0; q < 8; q++) s += expf(v[q] - mx);
  float ws = wave_sum(s);
  if ((threadIdx.x & 63) == 0) red2[wid] = ws;
  __syncthreads();
  float S = red2[0] + red2[1] + red2[2] + red2[3];
  float L = logf(S);
#pragma unroll
  for (int q = 0; q < 8; q++) p[threadIdx.x + 256 * q] = v[q] - mx - L;
  if (threadIdx.x == 0) out[(size_t)DREP * DREP + row] = (float)row;
}

extern "C" void kernel_launch(void* const* d_in, const int* in_sizes, int n_in,
                              void* d_out, int out_size, void* d_ws, size_t ws_size,
                              hipStream_t stream) {
  const float* in_tr = (const float*)d_in[0];
  const float* tg_tr = (const float*)d_in[1];
  const float* in_te = (const float*)d_in[2];
  const float* tg_te = (const float*)d_in[3];
  const float* W_fe  = (const float*)d_in[4];
  const float* b_fe  = (const float*)d_in[5];
  const float* W_lv  = (const float*)d_in[6];
  const float* b_lv  = (const float*)d_in[7];
  float* out = (float*)d_out;
  char* w = (char*)d_ws;

  ushort* wtT  = (ushort*)(w);                       //  1,048,576
  ushort* wlvT = (ushort*)(w + 1048576);             //  8,388,608
  float*  z    = (float*)(w + 9437184);              // 33,554,432
  ushort* zb   = (ushort*)(w + 42991616);            // 16,777,216
  float*  ctr  = (float*)(w + 59768832);             //      8,192
  float*  cte  = (float*)(w + 59777024);             //      8,192
  char*   zone2 = w + 59785216;
  ushort* xb   = (ushort*)zone2;                     // 134,217,728 (dead after FE)
  float*  lv   = (float*)zone2;                      // 33,554,432
  ushort* Am   = (ushort*)(zone2 + 33554432);        // 33,554,432
  ushort* Bm   = (ushort*)(zone2 + 67108864);        // 33,554,432

  const int half8 = 65536 * 512 / 8;  // 4,194,304
  k_conv<<<2048, 256, 0, stream>>>(in_tr, xb, half8);
  k_conv<<<2048, 256, 0, stream>>>(in_te, xb + (size_t)65536 * 512, half8);
  k_wt<<<1024, 256, 0, stream>>>(W_fe, wtT);
  k_wlvT<<<dim3(32, 32), 256, 0, stream>>>(W_lv, wlvT);

  // FE: M=131072, N=1024(pad), K=512 — fused stats epilogue
  gemm_nt<0><<<dim3(8, 1024), 256, 0, stream>>>(xb, wtT, IND, IND, IND,
                                                b_fe, z, zb, nullptr, nullptr);
  k_tgt<<<4096, 64, 0, stream>>>(tg_tr, tg_te, z, zb);

  // LV: M=4096, N=2048, K=2048
  gemm_nt<1><<<dim3(16, 32), 256, 0, stream>>>(zb, wlvT, DREP, DREP, DREP,
                                               b_lv, lv, nullptr, nullptr, nullptr);
  k_tf<<<4096, 256, 0, stream>>>(z, lv, Am, Bm, ctr, cte);

  // SC: M=2048, N=2048, K=8192
  gemm_nt<2><<<dim3(16, 16), 256, 0, stream>>>(Am, Bm, 4 * DREP, 4 * DREP, 4 * DREP,
                                               nullptr, out, nullptr, ctr, cte);
  k_sm<<<2048, 256, 0, stream>>>(out);
}

// Round 7
// 1189.716 us; speedup vs baseline: 4.3713x; 1.3770x over previous
//
#include <hip/hip_runtime.h>
#include <math.h>

// HolyLossNetwork round 7 = round 4 resubmit x3 (broker timeout x2, container
// failure x1; kernel never executed). FE GEMM restructured — block owns 128
// rows and iterates all 8 column tiles (A read once from HBM; B streamed from
// L2 through a 2x16KB double-buffered LDS tile). LV/SC keep the round-3 MFMA
// core. ws layout unchanged (185 MiB peak).

#define NEPI 2048
#define NSH  32
#define IND  512
#define NFEAT 1023
#define DREP 2048

typedef short s16x8 __attribute__((ext_vector_type(8)));
typedef float f32x4 __attribute__((ext_vector_type(4)));

__device__ __forceinline__ ushort f2bf(float f) {
  union { float f; unsigned u; } x; x.f = f;
  unsigned r = x.u + 0x7fffu + ((x.u >> 16) & 1u);
  return (ushort)(r >> 16);
}
__device__ __forceinline__ unsigned pack2(ushort a, ushort b) {
  return (unsigned)a | ((unsigned)b << 16);
}
__device__ __forceinline__ float wave_sum(float v) {
#pragma unroll
  for (int m = 1; m < 64; m <<= 1) v += __shfl_xor(v, m, 64);
  return v;
}
__device__ __forceinline__ float wave_max(float v) {
#pragma unroll
  for (int m = 1; m < 64; m <<= 1) v = fmaxf(v, __shfl_xor(v, m, 64));
  return v;
}

// ---------------- fp32 -> bf16 bulk convert (8 elems/thread/iter) ------------
__global__ __launch_bounds__(256) void k_conv(const float* __restrict__ src,
                                              ushort* __restrict__ dst, int n8) {
  int stride = gridDim.x * 256;
  for (int g = blockIdx.x * 256 + threadIdx.x; g < n8; g += stride) {
    const float4* s = (const float4*)src + 2 * (size_t)g;
    float4 a = s[0], b = s[1];
    uint4 o;
    o.x = pack2(f2bf(a.x), f2bf(a.y));
    o.y = pack2(f2bf(a.z), f2bf(a.w));
    o.z = pack2(f2bf(b.x), f2bf(b.y));
    o.w = pack2(f2bf(b.z), f2bf(b.w));
    *(uint4*)(dst + 8 * (size_t)g) = o;
  }
}

// ---------------- W_fe [512][1023] f32 -> wtT [1024][512] bf16 ----------------
__global__ __launch_bounds__(256) void k_wt(const float* __restrict__ w,
                                            ushort* __restrict__ wtT) {
  int f = blockIdx.x;          // 0..1023
  int k0 = threadIdx.x * 2;    // 0..510
  ushort2 o;
  if (f < NFEAT) {
    o.x = f2bf(w[(size_t)k0 * NFEAT + f]);
    o.y = f2bf(w[(size_t)(k0 + 1) * NFEAT + f]);
  } else {
    o.x = 0; o.y = 0;
  }
  *(ushort2*)&wtT[(size_t)f * IND + k0] = o;
}

// ---------------- W_lv [2048][2048] f32 -> wlvT [2048][2048] bf16 -------------
__global__ __launch_bounds__(256) void k_wlvT(const float* __restrict__ w,
                                              ushort* __restrict__ wT) {
  __shared__ float t[64][65];
  const int kb = blockIdx.x * 64, jb = blockIdx.y * 64;
  const int tid = threadIdx.x;
  {
    int c4 = (tid & 15) * 4;
#pragma unroll
    for (int i = 0; i < 4; i++) {
      int r = (tid >> 4) + i * 16;
      float4 v = *(const float4*)&w[(size_t)(kb + r) * DREP + jb + c4];
      t[r][c4 + 0] = v.x; t[r][c4 + 1] = v.y; t[r][c4 + 2] = v.z; t[r][c4 + 3] = v.w;
    }
  }
  __syncthreads();
  {
    int jr = tid >> 2;         // 0..63 output row (j)
    int kq = (tid & 3) * 16;   // k chunk
    ushort tmp[16];
#pragma unroll
    for (int q = 0; q < 16; q++) tmp[q] = f2bf(t[kq + q][jr]);
    uint4 o0, o1;
    o0.x = pack2(tmp[0], tmp[1]);   o0.y = pack2(tmp[2], tmp[3]);
    o0.z = pack2(tmp[4], tmp[5]);   o0.w = pack2(tmp[6], tmp[7]);
    o1.x = pack2(tmp[8], tmp[9]);   o1.y = pack2(tmp[10], tmp[11]);
    o1.z = pack2(tmp[12], tmp[13]); o1.w = pack2(tmp[14], tmp[15]);
    ushort* d = &wT[(size_t)(jb + jr) * DREP + kb + kq];
    *(uint4*)d = o0;
    *(uint4*)(d + 8) = o1;
  }
}

// ---------------- FE: 128 rows/block, internal loop over 8 col tiles ----------
// A-frags straight from global xb (L2-resident after first tile);
// B chunk [128 f][64 k] double-buffered in LDS, XOR-swizzled.
__global__ __launch_bounds__(256) void k_fe2(const ushort* __restrict__ xb,
                                             const ushort* __restrict__ wtT,
                                             const float* __restrict__ b_fe,
                                             float* __restrict__ z,
                                             ushort* __restrict__ zb) {
  __shared__ char bl[2][16384];
  const int tid = threadIdx.x;
  const int lane = tid & 63;
  const int w = tid >> 6;                 // wave 0..3
  const int l16 = lane & 15, lq = lane >> 4;
  const int row0 = blockIdx.x * 128 + w * 32;   // wave's 32 rows = 1 episode
  const int e = blockIdx.x * 4 + w;             // episode 0..4095

  const ushort* pa0 = xb + (size_t)(row0 + l16) * IND + lq * 8;
  const ushort* pa1 = pa0 + (size_t)16 * IND;

  // B staging: thread -> f = tid>>1, half = tid&1 (32 k-elems = 64B)
  const int sf = tid >> 1;
  const int sh = tid & 1;
  const int ssw = (sf & 7) << 4;
  char* const wb0 = bl[0] + sf * 128;
  char* const wb1 = bl[1] + sf * 128;
  const int rsw = (l16 & 7) << 4;

  for (int ct = 0; ct < 8; ct++) {
    f32x4 acc[2][8];
    const f32x4 zero = {0.f, 0.f, 0.f, 0.f};
#pragma unroll
    for (int m = 0; m < 2; m++)
#pragma unroll
      for (int n = 0; n < 8; n++) acc[m][n] = zero;

    const ushort* pbs = wtT + (size_t)(ct * 128 + sf) * IND + sh * 32;
    uint4 st[4];
#pragma unroll
    for (int q = 0; q < 4; q++) st[q] = *(const uint4*)(pbs + q * 8);
#pragma unroll
    for (int q = 0; q < 4; q++)
      *(uint4*)(wb0 + ((sh * 64 + q * 16) ^ ssw)) = st[q];

    for (int kc = 0; kc < 8; kc++) {
      __syncthreads();
      if (kc < 7) {
#pragma unroll
        for (int q = 0; q < 4; q++)
          st[q] = *(const uint4*)(pbs + (kc + 1) * 64 + q * 8);
      }
      const char* rb = bl[kc & 1];
#pragma unroll
      for (int ks = 0; ks < 2; ks++) {
        s16x8 a0 = *(const s16x8*)(pa0 + kc * 64 + ks * 32);
        s16x8 a1 = *(const s16x8*)(pa1 + kc * 64 + ks * 32);
#pragma unroll
        for (int n = 0; n < 8; n++) {
          int c = n * 16 + l16;
          s16x8 b = *(const s16x8*)(rb + c * 128 + ((ks * 64 + lq * 16) ^ rsw));
          acc[0][n] = __builtin_amdgcn_mfma_f32_16x16x32_bf16(a0, b, acc[0][n], 0, 0, 0);
          acc[1][n] = __builtin_amdgcn_mfma_f32_16x16x32_bf16(a1, b, acc[1][n], 0, 0, 0);
        }
      }
      if (kc < 7) {
        char* const wb = (kc & 1) ? wb0 : wb1;
#pragma unroll
        for (int q = 0; q < 4; q++)
          *(uint4*)(wb + ((sh * 64 + q * 16) ^ ssw)) = st[q];
      }
    }

    // stats epilogue for this 128-feature tile
#pragma unroll
    for (int n = 0; n < 8; n++) {
      int f = ct * 128 + n * 16 + l16;
      float Sa = 0.f, Sq = 0.f;
#pragma unroll
      for (int m = 0; m < 2; m++)
#pragma unroll
        for (int j = 0; j < 4; j++) {
          float v = acc[m][n][j];
          Sa += v; Sq += v * v;
        }
      Sa += __shfl_xor(Sa, 16, 64); Sq += __shfl_xor(Sq, 16, 64);
      Sa += __shfl_xor(Sa, 32, 64); Sq += __shfl_xor(Sq, 32, 64);
      if (lq == 0 && f < NFEAT) {
        float b = b_fe[f];
        float sphi = Sa + 32.f * b;
        float sphi2 = Sq + 2.f * b * Sa + 32.f * b * b;
        float mean = sphi * (1.f / 32.f);
        float var = (sphi2 - 32.f * mean * mean) * (1.f / 31.f);
        var = fmaxf(var, 0.f);
        float sd = sqrtf(var);
        z[(size_t)e * DREP + 1 + f] = mean;
        z[(size_t)e * DREP + 1025 + f] = sd;
        zb[(size_t)e * DREP + 1 + f] = f2bf(mean);
        zb[(size_t)e * DREP + 1025 + f] = f2bf(sd);
      }
    }
    __syncthreads();  // all reads of bl done before next ct's prologue write
  }
}

// ---------------- unified bf16 NT MFMA GEMM, 128x128 tile, BK=64 --------------
// MODE 1 = LV (bias+clip -> lv), MODE 2 = SC (0.5*acc + ctr + cte -> out).
template <int MODE>
__global__ __launch_bounds__(256) void gemm_nt(
    const ushort* __restrict__ A, const ushort* __restrict__ B,
    int lda, int ldb, int K,
    const float* __restrict__ bias,
    float* __restrict__ outf,
    const float* __restrict__ ctr, const float* __restrict__ cte) {
  __shared__ uint4 lsa4[1024];
  __shared__ uint4 lsb4[1024];
  char* const lsa = (char*)lsa4;
  char* const lsb = (char*)lsb4;
  const int tid = threadIdx.x;
  const int lane = tid & 63;
  const int wid = tid >> 6;
  const int wr = wid >> 1, wc = wid & 1;
  const int i0 = blockIdx.y * 128, j0 = blockIdx.x * 128;

  const int srow = tid >> 1;
  const int cb = (tid & 1) * 64;
  const int ssw = (srow & 7) << 4;
  const ushort* pa = A + (size_t)(i0 + srow) * lda + (tid & 1) * 32;
  const ushort* pb = B + (size_t)(j0 + srow) * ldb + (tid & 1) * 32;
  char* const wa = lsa + srow * 128;
  char* const wb = lsb + srow * 128;

  f32x4 acc[4][4];
  const f32x4 zero = {0.f, 0.f, 0.f, 0.f};
#pragma unroll
  for (int m = 0; m < 4; m++)
#pragma unroll
    for (int n = 0; n < 4; n++) acc[m][n] = zero;

  uint4 av[4], bv[4];
#pragma unroll
  for (int q = 0; q < 4; q++) {
    av[q] = *(const uint4*)(pa + q * 8);
    bv[q] = *(const uint4*)(pb + q * 8);
  }

  const int rswz = (lane & 7) << 4;
  const int ra_row = wr * 64 + (lane & 15);
  const int rb_row = wc * 64 + (lane & 15);
  const int kgrp = (lane >> 4) * 16;

  for (int kt = 0; kt < K; kt += 64) {
    __syncthreads();
#pragma unroll
    for (int q = 0; q < 4; q++) {
      *(uint4*)(wa + ((cb + q * 16) ^ ssw)) = av[q];
      *(uint4*)(wb + ((cb + q * 16) ^ ssw)) = bv[q];
    }
    __syncthreads();
    if (kt + 64 < K) {
#pragma unroll
      for (int q = 0; q < 4; q++) {
        av[q] = *(const uint4*)(pa + kt + 64 + q * 8);
        bv[q] = *(const uint4*)(pb + kt + 64 + q * 8);
      }
    }
#pragma unroll
    for (int ks = 0; ks < 2; ks++) {
      s16x8 af[4], bf[4];
#pragma unroll
      for (int m = 0; m < 4; m++) {
        int row = ra_row + m * 16;
        af[m] = *(const s16x8*)(lsa + row * 128 + ((ks * 64 + kgrp) ^ rswz));
      }
#pragma unroll
      for (int n = 0; n < 4; n++) {
        int row = rb_row + n * 16;
        bf[n] = *(const s16x8*)(lsb + row * 128 + ((ks * 64 + kgrp) ^ rswz));
      }
#pragma unroll
      for (int m = 0; m < 4; m++)
#pragma unroll
        for (int n = 0; n < 4; n++)
          acc[m][n] = __builtin_amdgcn_mfma_f32_16x16x32_bf16(af[m], bf[n], acc[m][n], 0, 0, 0);
    }
  }

#pragma unroll
  for (int m = 0; m < 4; m++) {
#pragma unroll
    for (int j = 0; j < 4; j++) {
      int i = i0 + wr * 64 + m * 16 + (lane >> 4) * 4 + j;
      float rowc = (MODE == 2) ? ctr[i] : 0.f;
#pragma unroll
      for (int n = 0; n < 4; n++) {
        int c = j0 + wc * 64 + n * 16 + (lane & 15);
        float v = acc[m][n][j];
        if constexpr (MODE == 1) {
          v += bias[c];
          v = fminf(fmaxf(v, -9.f), 1.f);
        } else {
          v = 0.5f * v + rowc + cte[c];
        }
        outf[(size_t)i * DREP + c] = v;
      }
    }
  }
}

// ---------------- targets column mean/std -> z/zb cols 0,1024 ----------------
__global__ __launch_bounds__(64) void k_tgt(const float* __restrict__ ttr,
                                            const float* __restrict__ tte,
                                            float* __restrict__ z,
                                            ushort* __restrict__ zb) {
  const int e = blockIdx.x;
  const int lane = threadIdx.x;
  const float* src = (e < NEPI) ? ttr + (size_t)e * NSH : tte + (size_t)(e - NEPI) * NSH;
  float v = (lane < NSH) ? src[lane] : 0.f;
  float s = v, q = v * v;
#pragma unroll
  for (int m = 1; m < 32; m <<= 1) {
    s += __shfl_xor(s, m, 64);
    q += __shfl_xor(q, m, 64);
  }
  if (lane == 0) {
    float mean = s * (1.f / 32.f);
    float var = (q - 32.f * mean * mean) * (1.f / 31.f);
    var = fmaxf(var, 0.f);
    float sd = sqrtf(var);
    z[(size_t)e * DREP + 0] = mean;
    z[(size_t)e * DREP + 1024] = sd;
    zb[(size_t)e * DREP + 0] = f2bf(mean);
    zb[(size_t)e * DREP + 1024] = f2bf(sd);
  }
}

// ---------------- KL operand matrices (bf16) + row scalars -------------------
__global__ __launch_bounds__(256) void k_tf(const float* __restrict__ z,
                                            const float* __restrict__ lv,
                                            ushort* __restrict__ Am,
                                            ushort* __restrict__ Bm,
                                            float* __restrict__ ctr,
                                            float* __restrict__ cte) {
  const int e = blockIdx.x;
  const bool train = e < NEPI;
  const int row = train ? e : e - NEPI;
  const float* zr = z + (size_t)e * DREP;
  const float* lr = lv + (size_t)e * DREP;
  ushort* o = (train ? Am : Bm) + (size_t)row * 4 * DREP;
  float ssum = 0.f, lsum = 0.f;
  for (int d = threadIdx.x; d < DREP; d += 256) {
    float mu = zr[d], l = lr[d];
    float ex = expf(l);
    float rx = expf(-l);
    float P = fmaf(mu, mu, ex);
    float t = mu * rx;
    if (train) {
      o[d] = f2bf(P);
      o[DREP + d] = f2bf(rx);
      o[2 * DREP + d] = f2bf(mu);
      o[3 * DREP + d] = f2bf(t);
    } else {
      o[d] = f2bf(rx);
      o[DREP + d] = f2bf(P);
      o[2 * DREP + d] = f2bf(-2.f * t);
      o[3 * DREP + d] = f2bf(-2.f * mu);
    }
    ssum += mu * mu * rx;
    lsum += l;
  }
  float s1 = wave_sum(ssum), s2 = wave_sum(lsum);
  __shared__ float rsa[4], rsb[4];
  int wid = threadIdx.x >> 6;
  if ((threadIdx.x & 63) == 0) { rsa[wid] = s1; rsb[wid] = s2; }
  __syncthreads();
  if (threadIdx.x == 0) {
    float S = rsa[0] + rsa[1] + rsa[2] + rsa[3];
    float L = rsb[0] + rsb[1] + rsb[2] + rsb[3];
    float c = 0.5f * S + L + 2905.98611600317f - 1024.0f;
    (train ? ctr : cte)[row] = c;
  }
}

// ---------------- in-place log_softmax(-score) + classes ---------------------
__global__ __launch_bounds__(256) void k_sm(float* __restrict__ out) {
  const int row = blockIdx.x;
  float* p = out + (size_t)row * DREP;
  float v[8];
  float mx = -1e30f;
#pragma unroll
  for (int q = 0; q < 8; q++) {
    v[q] = -p[threadIdx.x + 256 * q];
    mx = fmaxf(mx, v[q]);
  }
  __shared__ float red1[4], red2[4];
  float wm = wave_max(mx);
  int wid = threadIdx.x >> 6;
  if ((threadIdx.x & 63) == 0) red1[wid] = wm;
  __syncthreads();
  mx = fmaxf(fmaxf(red1[0], red1[1]), fmaxf(red1[2], red1[3]));
  float s = 0.f;
#pragma unroll
  for (int q = 0; q < 8; q++) s += expf(v[q] - mx);
  float ws = wave_sum(s);
  if ((threadIdx.x & 63) == 0) red2[wid] = ws;
  __syncthreads();
  float S = red2[0] + red2[1] + red2[2] + red2[3];
  float L = logf(S);
#pragma unroll
  for (int q = 0; q < 8; q++) p[threadIdx.x + 256 * q] = v[q] - mx - L;
  if (threadIdx.x == 0) out[(size_t)DREP * DREP + row] = (float)row;
}

extern "C" void kernel_launch(void* const* d_in, const int* in_sizes, int n_in,
                              void* d_out, int out_size, void* d_ws, size_t ws_size,
                              hipStream_t stream) {
  const float* in_tr = (const float*)d_in[0];
  const float* tg_tr = (const float*)d_in[1];
  const float* in_te = (const float*)d_in[2];
  const float* tg_te = (const float*)d_in[3];
  const float* W_fe  = (const float*)d_in[4];
  const float* b_fe  = (const float*)d_in[5];
  const float* W_lv  = (const float*)d_in[6];
  const float* b_lv  = (const float*)d_in[7];
  float* out = (float*)d_out;
  char* w = (char*)d_ws;

  ushort* wtT  = (ushort*)(w);                       //  1,048,576
  ushort* wlvT = (ushort*)(w + 1048576);             //  8,388,608
  float*  z    = (float*)(w + 9437184);              // 33,554,432
  ushort* zb   = (ushort*)(w + 42991616);            // 16,777,216
  float*  ctr  = (float*)(w + 59768832);             //      8,192
  float*  cte  = (float*)(w + 59777024);             //      8,192
  char*   zone2 = w + 59785216;
  ushort* xb   = (ushort*)zone2;                     // 134,217,728 (dead after FE)
  float*  lv   = (float*)zone2;                      // 33,554,432
  ushort* Am   = (ushort*)(zone2 + 33554432);        // 33,554,432
  ushort* Bm   = (ushort*)(zone2 + 67108864);        // 33,554,432

  const int half8 = 65536 * 512 / 8;  // 4,194,304
  k_conv<<<2048, 256, 0, stream>>>(in_tr, xb, half8);
  k_conv<<<2048, 256, 0, stream>>>(in_te, xb + (size_t)65536 * 512, half8);
  k_wt<<<1024, 256, 0, stream>>>(W_fe, wtT);
  k_wlvT<<<dim3(32, 32), 256, 0, stream>>>(W_lv, wlvT);

  // FE: 1024 blocks x 128 rows, internal loop over all 8 column tiles
  k_fe2<<<1024, 256, 0, stream>>>(xb, wtT, b_fe, z, zb);
  k_tgt<<<4096, 64, 0, stream>>>(tg_tr, tg_te, z, zb);

  // LV: M=4096, N=2048, K=2048
  gemm_nt<1><<<dim3(16, 32), 256, 0, stream>>>(zb, wlvT, DREP, DREP, DREP,
                                               b_lv, lv, nullptr, nullptr);
  k_tf<<<4096, 256, 0, stream>>>(z, lv, Am, Bm, ctr, cte);

  // SC: M=2048, N=2048, K=8192
  gemm_nt<2><<<dim3(16, 16), 256, 0, stream>>>(Am, Bm, 4 * DREP, 4 * DREP, 4 * DREP,
                                               nullptr, out, ctr, cte);
  k_sm<<<2048, 256, 0, stream>>>(out);
}